// Round 9
// baseline (693.215 us; speedup 1.0000x reference)
//
#include <hip/hip_runtime.h>
#include <math.h>

#define D_DIM 1024
#define FF_DIM 4096
#define N_SEQ 257
#define B_SZ 40
#define H_CNT 16
#define HD_DIM 64
#define M_TOK (B_SZ * N_SEQ)   // 10280
#define VT_NP 320               // padded key dim for vT (keys contiguous)

typedef unsigned short u16;
typedef __bf16 bf16x8 __attribute__((ext_vector_type(8)));
typedef float f32x4 __attribute__((ext_vector_type(4)));

__device__ __forceinline__ float b2f(u16 u) {
    union { unsigned int i; float f; } x; x.i = ((unsigned int)u) << 16; return x.f;
}
__device__ __forceinline__ u16 f2b(float f) {
    union { float f; unsigned int i; } x; x.f = f;
    unsigned int r = x.i + 0x7FFFu + ((x.i >> 16) & 1u);  // round-to-nearest-even
    return (u16)(r >> 16);
}

// async global->LDS 16B (dest = wave-uniform base + lane*16; contiguous layout)
__device__ __forceinline__ void g2lds16(const u16* g, u16* l) {
    __builtin_amdgcn_global_load_lds(
        (const __attribute__((address_space(1))) void*)g,
        (__attribute__((address_space(3))) void*)l,
        16, 0, 0);
}

// ---------------- fused fp32->bf16 weight conversion + bias concat ----------------
// wdst layout (contiguous): wqkv[3*nDD] | wo[nDD] | w1[nFD] | w2[nFD]
__global__ __launch_bounds__(256)
void cvt_all_kernel(const float* __restrict__ wq, const float* __restrict__ wk,
                    const float* __restrict__ wv, const float* __restrict__ wo,
                    const float* __restrict__ w1, const float* __restrict__ w2,
                    const float* __restrict__ bq, const float* __restrict__ bk,
                    const float* __restrict__ bv,
                    u16* __restrict__ wdst, float* __restrict__ bqkv) {
    const int nDD = D_DIM * D_DIM, nFD = FF_DIM * D_DIM;
    const int W8 = (4 * nDD + 2 * nFD) / 8;
    const int tid = blockIdx.x * 256 + threadIdx.x;
    if (tid < W8) {
        const int i = tid * 8;
        const float* src; int s;
        if (i < nDD)                { src = wq; s = i; }
        else if (i < 2 * nDD)       { src = wk; s = i - nDD; }
        else if (i < 3 * nDD)       { src = wv; s = i - 2 * nDD; }
        else if (i < 4 * nDD)       { src = wo; s = i - 3 * nDD; }
        else if (i < 4 * nDD + nFD) { src = w1; s = i - 4 * nDD; }
        else                        { src = w2; s = i - 4 * nDD - nFD; }
        float4 a = *(const float4*)(src + s);
        float4 b = *(const float4*)(src + s + 4);
        u16 o[8] = {f2b(a.x), f2b(a.y), f2b(a.z), f2b(a.w),
                    f2b(b.x), f2b(b.y), f2b(b.z), f2b(b.w)};
        *(uint4*)(wdst + i) = *(const uint4*)o;
    } else {
        const int j = tid - W8;
        if (j < 3 * D_DIM) {
            bqkv[j] = (j < D_DIM) ? bq[j]
                    : (j < 2 * D_DIM ? bk[j - D_DIM] : bv[j - 2 * D_DIM]);
        }
    }
}

// ---------------- LayerNorm: one block (256 thr) per token row of 1024 ----------------
__global__ __launch_bounds__(256)
void ln_kernel(const float* __restrict__ in, const float* __restrict__ w,
               const float* __restrict__ b, u16* __restrict__ out) {
    const int row = blockIdx.x;
    const int t = threadIdx.x;
    const size_t base = (size_t)row * D_DIM;
    float x[4];
#pragma unroll
    for (int i = 0; i < 4; ++i) x[i] = in[base + t + i * 256];
    float s  = x[0] + x[1] + x[2] + x[3];
    float ss = x[0]*x[0] + x[1]*x[1] + x[2]*x[2] + x[3]*x[3];
#pragma unroll
    for (int o = 32; o > 0; o >>= 1) {
        s  += __shfl_xor(s, o, 64);
        ss += __shfl_xor(ss, o, 64);
    }
    __shared__ float sh_s[4], sh_ss[4];
    const int wave = t >> 6, lane = t & 63;
    if (lane == 0) { sh_s[wave] = s; sh_ss[wave] = ss; }
    __syncthreads();
    float S  = sh_s[0] + sh_s[1] + sh_s[2] + sh_s[3];
    float SS = sh_ss[0] + sh_ss[1] + sh_ss[2] + sh_ss[3];
    float mean = S * (1.0f / D_DIM);
    float var  = SS * (1.0f / D_DIM) - mean * mean;
    float rstd = rsqrtf(var + 1e-5f);
#pragma unroll
    for (int i = 0; i < 4; ++i) {
        int idx = t + i * 256;
        float y = (x[i] - mean) * rstd * w[idx] + b[idx];
        out[base + idx] = f2b(y);
    }
}

// ---------------- GEMM 128x128 (m97 structure) + XCD-pinning block swizzle ----------
// Swizzle (n INNERMOST): within a chunk of sw m-tiles, n0 = rem % nN varies fastest.
// All nN values are divisible by 8, so with round-robin lid->XCD each XCD only ever
// sees n == (lid mod 8) mod 8 -> its B-subset (nN/8 tiles, ~1 MB) stays pinned in
// that XCD's 4 MB L2 for the entire dispatch; A-tiles are shared by nN consecutive
// lids (all XCDs, near-simultaneous) and stream through L3 once.
// MODE 0: out_bf16 = acc+bias
// MODE 2: out_f32  = extra_f32 + acc + bias     (o proj / fc2 + residual)
// MODE 3: out_bf16 = quickgelu(acc+bias)        (fc1)
// MODE 5: QKV fused (N=3072): seg0 -> q*0.125, seg1 -> k, seg2 -> vT scatter
template <int MODE>
__global__ __launch_bounds__(256)
void gemm_kernel(const u16* __restrict__ A, const u16* __restrict__ Bt,
                 const float* __restrict__ bias, const float* __restrict__ extra,
                 void* __restrict__ out, u16* __restrict__ out2, u16* __restrict__ out3,
                 int M, int N, int K, int sw) {
    __shared__ __align__(16) u16 sA[128 * 64];
    __shared__ __align__(16) u16 sB[128 * 64];
    const int t = threadIdx.x;

    // block swizzle: n innermost (XCD-pinned B), chunks of sw m-tiles
    const int nM = gridDim.x, nN = gridDim.y;
    const int lid   = blockIdx.y * nM + blockIdx.x;   // dispatch order (x fastest)
    const int csz   = sw * nN;
    const int chunk = lid / csz;
    const int rem   = lid - chunk * csz;
    const int n0 = (rem % nN) * 128;
    const int m0 = (chunk * sw + rem / nN) * 128;     // last chunk auto-shrinks

    const int wave = t >> 6, lane = t & 63;
    const int quad = lane >> 4, l16 = lane & 15;
    const int wm = (wave >> 1) * 64, wn = (wave & 1) * 64;

    const u16* gA[4]; const u16* gB[4]; u16* lA[4]; u16* lB[4];
#pragma unroll
    for (int i = 0; i < 4; ++i) {
        const int c = i * 256 + t;
        const int row = c >> 3;
        const int sg = (c & 7) ^ (row & 7);   // XOR-swizzled global k-segment
        int gr = m0 + row; if (gr > M - 1) gr = M - 1;
        gA[i] = A  + (size_t)gr * K + sg * 8;
        gB[i] = Bt + (size_t)(n0 + row) * K + sg * 8;
        lA[i] = sA + c * 8;
        lB[i] = sB + c * 8;
    }

    f32x4 acc[4][4];
#pragma unroll
    for (int mt = 0; mt < 4; ++mt)
#pragma unroll
        for (int nt = 0; nt < 4; ++nt) acc[mt][nt] = {0.f, 0.f, 0.f, 0.f};

    for (int k0 = 0; k0 < K; k0 += 64) {
        __syncthreads();
#pragma unroll
        for (int i = 0; i < 4; ++i) g2lds16(gA[i] + k0, lA[i]);
#pragma unroll
        for (int i = 0; i < 4; ++i) g2lds16(gB[i] + k0, lB[i]);
        __syncthreads();
#pragma unroll
        for (int j = 0; j < 2; ++j) {
            bf16x8 af[4], bfr[4];
#pragma unroll
            for (int mt = 0; mt < 4; ++mt) {
                const int r = wm + mt * 16 + l16;
                af[mt] = *(const bf16x8*)(sA + r * 64 + ((j * 4 + quad) ^ (r & 7)) * 8);
            }
#pragma unroll
            for (int nt = 0; nt < 4; ++nt) {
                const int n = wn + nt * 16 + l16;
                bfr[nt] = *(const bf16x8*)(sB + n * 64 + ((j * 4 + quad) ^ (n & 7)) * 8);
            }
#pragma unroll
            for (int mt = 0; mt < 4; ++mt)
#pragma unroll
                for (int nt = 0; nt < 4; ++nt)
                    acc[mt][nt] = __builtin_amdgcn_mfma_f32_16x16x32_bf16(
                        af[mt], bfr[nt], acc[mt][nt], 0, 0, 0);
        }
    }

    // C/D layout: col = lane&15, row = quad*4 + reg
#pragma unroll
    for (int mt = 0; mt < 4; ++mt) {
#pragma unroll
        for (int nt = 0; nt < 4; ++nt) {
            const int n = n0 + wn + nt * 16 + l16;
            const float bvf = bias[n];
#pragma unroll
            for (int i = 0; i < 4; ++i) {
                const int m = m0 + wm + mt * 16 + quad * 4 + i;
                if (m >= M) continue;
                float v = acc[mt][nt][i] + bvf;
                if (MODE == 0) {
                    ((u16*)out)[(size_t)m * N + n] = f2b(v);
                } else if (MODE == 2) {
                    const size_t idx = (size_t)m * N + n;
                    ((float*)out)[idx] = extra[idx] + v;
                } else if (MODE == 3) {
                    float g = v / (1.0f + __expf(-1.702f * v));
                    ((u16*)out)[(size_t)m * N + n] = f2b(g);
                } else {  // MODE 5: fused QKV split
                    const int seg = n >> 10, nl = n & 1023;
                    if (seg == 0) {
                        ((u16*)out)[(size_t)m * D_DIM + nl] = f2b(v * 0.125f);
                    } else if (seg == 1) {
                        out2[(size_t)m * D_DIM + nl] = f2b(v);
                    } else {
                        // vT[b*1024 + channel][tok_in_batch], keys contiguous
                        const int bb = m / N_SEQ;
                        const int tt = m - bb * N_SEQ;
                        out3[((size_t)bb * D_DIM + nl) * VT_NP + tt] = f2b(v);
                    }
                }
            }
        }
    }
}

// ---------------- MFMA attention v4: XCD-affine grid, 38KB LDS, one barrier ----------
// 1-D grid of 3200; decode puts the 5 q-tile blocks of one (b,h) on the SAME XCD
// (ids == same mod 8, 8 apart) so K/vT stay L2-resident.
// P stride 296 (=8*37): 2-way max banks on b128 reads (free). Max col 287 < 296.
// __syncthreads() after softmax is REQUIRED: sP is stored via u16* and read via
// __bf16-vector loads; without the barrier the compiler may reorder them (TBAA).
#define ATT_PS 296
__global__ __launch_bounds__(256, 4)
void attn_mfma_kernel(const u16* __restrict__ q, const u16* __restrict__ k,
                      const u16* __restrict__ vT, u16* __restrict__ o) {
    __shared__ __align__(16) u16 sP[64 * ATT_PS];   // 37 KB
    __shared__ float sInv[64];

    const int t = threadIdx.x;
    const int wave = t >> 6, lane = t & 63;
    const int quad = lane >> 4, l16 = lane & 15;

    // XCD-affine decode: lid = g*40 + qt*8 + x ; hb = g*8 + x
    const int lid = blockIdx.x;
    const int g = lid / 40, local = lid - g * 40;
    const int qt = local >> 3, x = local & 7;
    const int hb = g * 8 + x;
    const int h = hb & (H_CNT - 1), b = hb >> 4;
    const int q0 = qt * 64;
    const size_t head = (size_t)b * N_SEQ * D_DIM + (size_t)h * HD_DIM;

    int qrow = q0 + wave * 16 + l16; if (qrow > N_SEQ - 1) qrow = N_SEQ - 1;
    const u16* qp = q + head + (size_t)qrow * D_DIM + quad * 8;
    bf16x8 qf0 = *(const bf16x8*)(qp);
    bf16x8 qf1 = *(const bf16x8*)(qp + 32);

    // ---- Phase 1: S = Q K^T (keys 0..287; kt=4 only nt<2) ----
    f32x4 s[5][4];
#pragma unroll
    for (int kt = 0; kt < 5; ++kt) {
        const int ntMax = (kt == 4) ? 2 : 4;
#pragma unroll
        for (int nt = 0; nt < 4; ++nt) {
            if (nt >= ntMax) continue;
            s[kt][nt] = {0.f, 0.f, 0.f, 0.f};
            int key = kt * 64 + nt * 16 + l16;
            if (key > N_SEQ - 1) key = N_SEQ - 1;
            const u16* kr = k + head + (size_t)key * D_DIM + quad * 8;
            bf16x8 b0 = *(const bf16x8*)(kr);
            bf16x8 b1 = *(const bf16x8*)(kr + 32);
            s[kt][nt] = __builtin_amdgcn_mfma_f32_16x16x32_bf16(qf0, b0, s[kt][nt], 0, 0, 0);
            s[kt][nt] = __builtin_amdgcn_mfma_f32_16x16x32_bf16(qf1, b1, s[kt][nt], 0, 0, 0);
        }
    }

    // ---- Phase 2: softmax in registers; store unnormalized P (bf16) ----
#pragma unroll
    for (int i = 0; i < 4; ++i) {
        float mx = -1e30f;
#pragma unroll
        for (int kt = 0; kt < 5; ++kt) {
            const int ntMax = (kt == 4) ? 2 : 4;
#pragma unroll
            for (int nt = 0; nt < 4; ++nt) {
                if (nt >= ntMax) continue;
                const bool valid = (kt < 4) || (nt == 0 && l16 == 0);  // col < 257
                if (valid) mx = fmaxf(mx, s[kt][nt][i]);
            }
        }
        mx = fmaxf(mx, __shfl_xor(mx, 1, 64));
        mx = fmaxf(mx, __shfl_xor(mx, 2, 64));
        mx = fmaxf(mx, __shfl_xor(mx, 4, 64));
        mx = fmaxf(mx, __shfl_xor(mx, 8, 64));
        float sum = 0.f;
        const int prow = wave * 16 + quad * 4 + i;
#pragma unroll
        for (int kt = 0; kt < 5; ++kt) {
            const int ntMax = (kt == 4) ? 2 : 4;
#pragma unroll
            for (int nt = 0; nt < 4; ++nt) {
                if (nt >= ntMax) continue;
                const bool valid = (kt < 4) || (nt == 0 && l16 == 0);
                float pv = 0.f;
                if (valid) { pv = __expf(s[kt][nt][i] - mx); sum += pv; }
                sP[prow * ATT_PS + kt * 64 + nt * 16 + l16] = f2b(pv);
            }
        }
        sum += __shfl_xor(sum, 1, 64);
        sum += __shfl_xor(sum, 2, 64);
        sum += __shfl_xor(sum, 4, 64);
        sum += __shfl_xor(sum, 8, 64);
        if (l16 == 0) sInv[prow] = 1.0f / sum;
    }
    __syncthreads();   // required: orders u16 stores vs bf16-vector loads of sP

    // ---- Phase 3: O = P~ V via vT, scale by 1/sum in epilogue ----
    f32x4 oacc[4] = {{0.f,0.f,0.f,0.f},{0.f,0.f,0.f,0.f},
                     {0.f,0.f,0.f,0.f},{0.f,0.f,0.f,0.f}};
    const u16* vhead = vT + ((size_t)b * D_DIM + h * HD_DIM) * VT_NP;
    const int prr = wave * 16 + l16;     // P row this lane reads (A-operand m)
#pragma unroll
    for (int kt = 0; kt < 5; ++kt) {
        const int j0 = kt * 64;
        bf16x8 p0 = *(const bf16x8*)(sP + prr * ATT_PS + j0 + quad * 8);
        bf16x8 p1;
        if (kt < 4) p1 = *(const bf16x8*)(sP + prr * ATT_PS + j0 + quad * 8 + 32);
#pragma unroll
        for (int nt = 0; nt < 4; ++nt) {
            const u16* vr = vhead + (size_t)(nt * 16 + l16) * VT_NP + j0 + quad * 8;
            bf16x8 b0 = *(const bf16x8*)(vr);
            oacc[nt] = __builtin_amdgcn_mfma_f32_16x16x32_bf16(p0, b0, oacc[nt], 0, 0, 0);
            if (kt < 4) {
                bf16x8 b1 = *(const bf16x8*)(vr + 32);
                oacc[nt] = __builtin_amdgcn_mfma_f32_16x16x32_bf16(p1, b1, oacc[nt], 0, 0, 0);
            }
        }
    }
#pragma unroll
    for (int nt = 0; nt < 4; ++nt) {
#pragma unroll
        for (int i = 0; i < 4; ++i) {
            const int mrow = wave * 16 + quad * 4 + i;
            const int m = q0 + mrow;
            if (m < N_SEQ) {
                o[head + (size_t)m * D_DIM + nt * 16 + l16] =
                    f2b(oacc[nt][i] * sInv[mrow]);
            }
        }
    }
}

extern "C" void kernel_launch(void* const* d_in, const int* in_sizes, int n_in,
                              void* d_out, int out_size, void* d_ws, size_t ws_size,
                              hipStream_t stream) {
    const float* hs   = (const float*)d_in[0];
    const float* ln1w = (const float*)d_in[1];
    const float* ln1b = (const float*)d_in[2];
    const float* wq   = (const float*)d_in[3];
    const float* bq   = (const float*)d_in[4];
    const float* wk   = (const float*)d_in[5];
    const float* bk   = (const float*)d_in[6];
    const float* wv   = (const float*)d_in[7];
    const float* bv   = (const float*)d_in[8];
    const float* wo   = (const float*)d_in[9];
    const float* bo   = (const float*)d_in[10];
    const float* ln2w = (const float*)d_in[11];
    const float* ln2b = (const float*)d_in[12];
    const float* w1   = (const float*)d_in[13];
    const float* b1   = (const float*)d_in[14];
    const float* w2   = (const float*)d_in[15];
    const float* b2   = (const float*)d_in[16];

    char* p = (char*)d_ws;
    size_t off = 0;
    auto alloc = [&](size_t bytes) {
        char* r = p + off;
        off += (bytes + 255) & ~(size_t)255;
        return (void*)r;
    };
    const int M = M_TOK;
    // weight block: MUST stay contiguous in this order (cvt_all writes linearly)
    u16* wqkvb = (u16*)alloc((size_t)3 * D_DIM * D_DIM * 2);  // [3072][1024]
    u16* wob   = (u16*)alloc((size_t)D_DIM * D_DIM * 2);
    u16* w1b   = (u16*)alloc((size_t)FF_DIM * D_DIM * 2);
    u16* w2b   = (u16*)alloc((size_t)D_DIM * FF_DIM * 2);
    float* bqkv = (float*)alloc((size_t)3 * D_DIM * 4);
    u16*  x_ln = (u16*) alloc((size_t)M * D_DIM * 2);
    u16*  qb   = (u16*) alloc((size_t)M * D_DIM * 2);
    u16*  kb   = (u16*) alloc((size_t)M * D_DIM * 2);
    u16*  vTb  = (u16*) alloc((size_t)B_SZ * D_DIM * VT_NP * 2);  // 26.2 MB
    u16*  ab   = (u16*) alloc((size_t)M * D_DIM * 2);
    float* hid = (float*)alloc((size_t)M * D_DIM * 4);
    u16*  h1   = qb;  // qb+kb+vT+ab span 89 MB >= M*FF*2 = 84 MB; all dead by FC1

    const int nDD = D_DIM * D_DIM, nFD = FF_DIM * D_DIM;
    const int W8 = (4 * nDD + 2 * nFD) / 8;
    cvt_all_kernel<<<(W8 + 3 * D_DIM + 255) / 256, 256, 0, stream>>>(
        wq, wk, wv, wo, w1, w2, bq, bk, bv, wqkvb, bqkv);

    ln_kernel<<<M, 256, 0, stream>>>(hs, ln1w, ln1b, x_ln);

    const int gM = (M + 127) / 128;  // 81
    dim3 gQKV(gM, 3 * D_DIM / 128);  // 81 x 24
    gemm_kernel<5><<<gQKV, 256, 0, stream>>>(x_ln, wqkvb, bqkv, nullptr,
                                             qb, kb, vTb, M, 3 * D_DIM, D_DIM, 16);

    attn_mfma_kernel<<<5 * H_CNT * B_SZ, 256, 0, stream>>>(qb, kb, vTb, ab);

    dim3 gD(gM, D_DIM / 128);        // 81 x 8
    gemm_kernel<2><<<gD, 256, 0, stream>>>(ab, wob, bo, hs, hid, nullptr, nullptr,
                                           M, D_DIM, D_DIM, 16);

    ln_kernel<<<M, 256, 0, stream>>>(hid, ln2w, ln2b, x_ln);

    dim3 gF(gM, FF_DIM / 128);       // 81 x 32
    gemm_kernel<3><<<gF, 256, 0, stream>>>(x_ln, w1b, b1, nullptr, h1, nullptr, nullptr,
                                           M, FF_DIM, D_DIM, 16);
    gemm_kernel<2><<<gD, 256, 0, stream>>>(h1, w2b, b2, hid, (float*)d_out,
                                           nullptr, nullptr, M, D_DIM, FF_DIM, 4);
}

// Round 11
// 599.481 us; speedup vs baseline: 1.1564x; 1.1564x over previous
//
#include <hip/hip_runtime.h>
#include <math.h>

#define D_DIM 1024
#define FF_DIM 4096
#define N_SEQ 257
#define B_SZ 40
#define H_CNT 16
#define HD_DIM 64
#define M_TOK (B_SZ * N_SEQ)   // 10280
#define VT_NP 320               // padded key dim for vT (keys contiguous)

typedef unsigned short u16;
typedef unsigned char u8;
typedef __bf16 bf16x8 __attribute__((ext_vector_type(8)));
typedef float f32x4 __attribute__((ext_vector_type(4)));
typedef int i32x4 __attribute__((ext_vector_type(4)));

__device__ __forceinline__ float b2f(u16 u) {
    union { unsigned int i; float f; } x; x.i = ((unsigned int)u) << 16; return x.f;
}
__device__ __forceinline__ u16 f2b(float f) {
    union { float f; unsigned int i; } x; x.f = f;
    unsigned int r = x.i + 0x7FFFu + ((x.i >> 16) & 1u);  // round-to-nearest-even
    return (u16)(r >> 16);
}
// float -> signed i8 (RNE, clamp +-127), returned as low byte
__device__ __forceinline__ unsigned q8(float f, float s) {
    int q = __float2int_rn(f * s);
    q = q < -127 ? -127 : (q > 127 ? 127 : q);
    return (unsigned)q & 0xFFu;
}

// async global->LDS 16B (dest = wave-uniform base + lane*16; contiguous layout)
__device__ __forceinline__ void g2lds16(const void* g, void* l) {
    __builtin_amdgcn_global_load_lds(
        (const __attribute__((address_space(1))) void*)g,
        (__attribute__((address_space(3))) void*)l,
        16, 0, 0);
}

// ---------------- fused weight conversion + bias concat ----------------
// bf16 dst (contiguous): wqkv[3*nDD] | wo[nDD].  i8 dst: w1i8 (x1024), w2i8 (x1024).
__global__ __launch_bounds__(256)
void cvt_all_kernel(const float* __restrict__ wq, const float* __restrict__ wk,
                    const float* __restrict__ wv, const float* __restrict__ wo,
                    const float* __restrict__ w1, const float* __restrict__ w2,
                    const float* __restrict__ bq, const float* __restrict__ bk,
                    const float* __restrict__ bv,
                    u16* __restrict__ wdst, u8* __restrict__ w1i8,
                    u8* __restrict__ w2i8, float* __restrict__ bqkv) {
    const int nDD = D_DIM * D_DIM, nFD = FF_DIM * D_DIM;
    const int WB8 = (4 * nDD) / 8;       // bf16 8-elem chunks
    const int WF8 = (2 * nFD) / 8;       // i8 8-elem chunks
    const int tid = blockIdx.x * 256 + threadIdx.x;
    if (tid < WB8) {
        const int i = tid * 8;
        const float* src; int s;
        if (i < nDD)          { src = wq; s = i; }
        else if (i < 2 * nDD) { src = wk; s = i - nDD; }
        else if (i < 3 * nDD) { src = wv; s = i - 2 * nDD; }
        else                  { src = wo; s = i - 3 * nDD; }
        float4 a = *(const float4*)(src + s);
        float4 b = *(const float4*)(src + s + 4);
        u16 o[8] = {f2b(a.x), f2b(a.y), f2b(a.z), f2b(a.w),
                    f2b(b.x), f2b(b.y), f2b(b.z), f2b(b.w)};
        *(uint4*)(wdst + i) = *(const uint4*)o;
    } else if (tid < WB8 + WF8) {
        const int j = (tid - WB8) * 8;
        const float* src; u8* dst; int s;
        if (j < nFD) { src = w1; dst = w1i8; s = j; }
        else         { src = w2; dst = w2i8; s = j - nFD; }
        float4 a = *(const float4*)(src + s);
        float4 b = *(const float4*)(src + s + 4);
        const float sc = 1024.f;
        unsigned lo = q8(a.x, sc) | (q8(a.y, sc) << 8) |
                      (q8(a.z, sc) << 16) | (q8(a.w, sc) << 24);
        unsigned hi = q8(b.x, sc) | (q8(b.y, sc) << 8) |
                      (q8(b.z, sc) << 16) | (q8(b.w, sc) << 24);
        uint2 pk = {lo, hi};
        *(uint2*)(dst + s) = pk;
    } else {
        const int j = tid - WB8 - WF8;
        if (j < 3 * D_DIM) {
            bqkv[j] = (j < D_DIM) ? bq[j]
                    : (j < 2 * D_DIM ? bk[j - D_DIM] : bv[j - 2 * D_DIM]);
        }
    }
}

// ---------------- LayerNorm: one block (256 thr) per token row of 1024 ----------------
// I8OUT=false -> bf16 out (u16*), I8OUT=true -> i8 out x16 (u8*)
template <bool I8OUT>
__global__ __launch_bounds__(256)
void ln_kernel(const float* __restrict__ in, const float* __restrict__ w,
               const float* __restrict__ b, void* __restrict__ out) {
    const int row = blockIdx.x;
    const int t = threadIdx.x;
    const size_t base = (size_t)row * D_DIM;
    float x[4];
#pragma unroll
    for (int i = 0; i < 4; ++i) x[i] = in[base + t + i * 256];
    float s  = x[0] + x[1] + x[2] + x[3];
    float ss = x[0]*x[0] + x[1]*x[1] + x[2]*x[2] + x[3]*x[3];
#pragma unroll
    for (int o = 32; o > 0; o >>= 1) {
        s  += __shfl_xor(s, o, 64);
        ss += __shfl_xor(ss, o, 64);
    }
    __shared__ float sh_s[4], sh_ss[4];
    const int wave = t >> 6, lane = t & 63;
    if (lane == 0) { sh_s[wave] = s; sh_ss[wave] = ss; }
    __syncthreads();
    float S  = sh_s[0] + sh_s[1] + sh_s[2] + sh_s[3];
    float SS = sh_ss[0] + sh_ss[1] + sh_ss[2] + sh_ss[3];
    float mean = S * (1.0f / D_DIM);
    float var  = SS * (1.0f / D_DIM) - mean * mean;
    float rstd = rsqrtf(var + 1e-5f);
#pragma unroll
    for (int i = 0; i < 4; ++i) {
        int idx = t + i * 256;
        float y = (x[i] - mean) * rstd * w[idx] + b[idx];
        if (I8OUT) ((u8*)out)[base + idx]  = (u8)q8(y, 16.f);
        else       ((u16*)out)[base + idx] = f2b(y);
    }
}

// ---------------- bf16 GEMM 128x128 (m97 structure) + XCD-pinning swizzle ----------
// MODE 2: out_f32 = extra_f32 + acc + bias     (o proj + residual)
// MODE 5: QKV fused (N=3072): seg0 -> q*0.125, seg1 -> k, seg2 -> vT scatter
template <int MODE>
__global__ __launch_bounds__(256)
void gemm_kernel(const u16* __restrict__ A, const u16* __restrict__ Bt,
                 const float* __restrict__ bias, const float* __restrict__ extra,
                 void* __restrict__ out, u16* __restrict__ out2, u16* __restrict__ out3,
                 int M, int N, int K, int sw) {
    __shared__ __align__(16) u16 sA[128 * 64];
    __shared__ __align__(16) u16 sB[128 * 64];
    const int t = threadIdx.x;

    // block swizzle: n innermost (XCD-pinned B), chunks of sw m-tiles
    const int nM = gridDim.x, nN = gridDim.y;
    const int lid   = blockIdx.y * nM + blockIdx.x;
    const int csz   = sw * nN;
    const int chunk = lid / csz;
    const int rem   = lid - chunk * csz;
    const int n0 = (rem % nN) * 128;
    const int m0 = (chunk * sw + rem / nN) * 128;

    const int wave = t >> 6, lane = t & 63;
    const int quad = lane >> 4, l16 = lane & 15;
    const int wm = (wave >> 1) * 64, wn = (wave & 1) * 64;

    const u16* gA[4]; const u16* gB[4]; u16* lA[4]; u16* lB[4];
#pragma unroll
    for (int i = 0; i < 4; ++i) {
        const int c = i * 256 + t;
        const int row = c >> 3;
        const int sg = (c & 7) ^ (row & 7);
        int gr = m0 + row; if (gr > M - 1) gr = M - 1;
        gA[i] = A  + (size_t)gr * K + sg * 8;
        gB[i] = Bt + (size_t)(n0 + row) * K + sg * 8;
        lA[i] = sA + c * 8;
        lB[i] = sB + c * 8;
    }

    f32x4 acc[4][4];
#pragma unroll
    for (int mt = 0; mt < 4; ++mt)
#pragma unroll
        for (int nt = 0; nt < 4; ++nt) acc[mt][nt] = {0.f, 0.f, 0.f, 0.f};

    for (int k0 = 0; k0 < K; k0 += 64) {
        __syncthreads();
#pragma unroll
        for (int i = 0; i < 4; ++i) g2lds16(gA[i] + k0, lA[i]);
#pragma unroll
        for (int i = 0; i < 4; ++i) g2lds16(gB[i] + k0, lB[i]);
        __syncthreads();
#pragma unroll
        for (int j = 0; j < 2; ++j) {
            bf16x8 af[4], bfr[4];
#pragma unroll
            for (int mt = 0; mt < 4; ++mt) {
                const int r = wm + mt * 16 + l16;
                af[mt] = *(const bf16x8*)(sA + r * 64 + ((j * 4 + quad) ^ (r & 7)) * 8);
            }
#pragma unroll
            for (int nt = 0; nt < 4; ++nt) {
                const int n = wn + nt * 16 + l16;
                bfr[nt] = *(const bf16x8*)(sB + n * 64 + ((j * 4 + quad) ^ (n & 7)) * 8);
            }
#pragma unroll
            for (int mt = 0; mt < 4; ++mt)
#pragma unroll
                for (int nt = 0; nt < 4; ++nt)
                    acc[mt][nt] = __builtin_amdgcn_mfma_f32_16x16x32_bf16(
                        af[mt], bfr[nt], acc[mt][nt], 0, 0, 0);
        }
    }

#pragma unroll
    for (int mt = 0; mt < 4; ++mt) {
#pragma unroll
        for (int nt = 0; nt < 4; ++nt) {
            const int n = n0 + wn + nt * 16 + l16;
            const float bvf = bias[n];
#pragma unroll
            for (int i = 0; i < 4; ++i) {
                const int m = m0 + wm + mt * 16 + quad * 4 + i;
                if (m >= M) continue;
                float v = acc[mt][nt][i] + bvf;
                if (MODE == 2) {
                    const size_t idx = (size_t)m * N + n;
                    ((float*)out)[idx] = extra[idx] + v;
                } else {  // MODE 5
                    const int seg = n >> 10, nl = n & 1023;
                    if (seg == 0) {
                        ((u16*)out)[(size_t)m * D_DIM + nl] = f2b(v * 0.125f);
                    } else if (seg == 1) {
                        out2[(size_t)m * D_DIM + nl] = f2b(v);
                    } else {
                        const int bb = m / N_SEQ;
                        const int tt = m - bb * N_SEQ;
                        out3[((size_t)bb * D_DIM + nl) * VT_NP + tt] = f2b(v);
                    }
                }
            }
        }
    }
}

// ---------------- i8 GEMM 128x128, BK=128, mfma_i32_16x16x64_i8 ----------------
// A i8 [M,K] (scale sA_inv folded in epilogue), Bt i8 [N,K] (x1024).
// Fragment: A[m=l16][k = j*64 + quad*16 + byte] -> LDS slot (j*4+quad)^(r&7), 16B.
// MODE 2: out_f32 = extra_f32 + acc/32768 + bias   (fc2 + residual -> d_out)
// MODE 3: out_i8  = quickgelu(acc/16384 + bias) x32  (fc1 -> h1i8)
template <int MODE>
__global__ __launch_bounds__(256)
void gemm_i8_kernel(const u8* __restrict__ A, const u8* __restrict__ Bt,
                    const float* __restrict__ bias, const float* __restrict__ extra,
                    void* __restrict__ out, int M, int N, int K, int sw) {
    __shared__ __align__(16) u8 sA[128 * 128];   // 16 KB
    __shared__ __align__(16) u8 sB[128 * 128];   // 16 KB
    const int t = threadIdx.x;

    const int nM = gridDim.x, nN = gridDim.y;
    const int lid   = blockIdx.y * nM + blockIdx.x;
    const int csz   = sw * nN;
    const int chunk = lid / csz;
    const int rem   = lid - chunk * csz;
    const int n0 = (rem % nN) * 128;
    const int m0 = (chunk * sw + rem / nN) * 128;

    const int wave = t >> 6, lane = t & 63;
    const int quad = lane >> 4, l16 = lane & 15;
    const int wm = (wave >> 1) * 64, wn = (wave & 1) * 64;

    // staging: chunk c = i*256+t covers LDS bytes [c*16, +16); row=c>>3, slot=c&7
    const u8* gA[4]; const u8* gB[4]; u8* lA[4]; u8* lB[4];
#pragma unroll
    for (int i = 0; i < 4; ++i) {
        const int c = i * 256 + t;
        const int row = c >> 3;
        const int sg = (c & 7) ^ (row & 7);   // XOR-swizzled global 16B-segment
        int gr = m0 + row; if (gr > M - 1) gr = M - 1;
        gA[i] = A  + (size_t)gr * K + sg * 16;
        gB[i] = Bt + (size_t)(n0 + row) * K + sg * 16;
        lA[i] = sA + c * 16;
        lB[i] = sB + c * 16;
    }

    i32x4 acc[4][4];
#pragma unroll
    for (int mt = 0; mt < 4; ++mt)
#pragma unroll
        for (int nt = 0; nt < 4; ++nt) acc[mt][nt] = {0, 0, 0, 0};

    for (int k0 = 0; k0 < K; k0 += 128) {
        __syncthreads();
#pragma unroll
        for (int i = 0; i < 4; ++i) g2lds16(gA[i] + k0, lA[i]);
#pragma unroll
        for (int i = 0; i < 4; ++i) g2lds16(gB[i] + k0, lB[i]);
        __syncthreads();
#pragma unroll
        for (int j = 0; j < 2; ++j) {
            i32x4 af[4], bfr[4];
#pragma unroll
            for (int mt = 0; mt < 4; ++mt) {
                const int r = wm + mt * 16 + l16;
                af[mt] = *(const i32x4*)(sA + r * 128 + (((j * 4 + quad) ^ (r & 7)) * 16));
            }
#pragma unroll
            for (int nt = 0; nt < 4; ++nt) {
                const int n = wn + nt * 16 + l16;
                bfr[nt] = *(const i32x4*)(sB + n * 128 + (((j * 4 + quad) ^ (n & 7)) * 16));
            }
#pragma unroll
            for (int mt = 0; mt < 4; ++mt)
#pragma unroll
                for (int nt = 0; nt < 4; ++nt)
                    acc[mt][nt] = __builtin_amdgcn_mfma_i32_16x16x64_i8(
                        af[mt], bfr[nt], acc[mt][nt], 0, 0, 0);
        }
    }

    // C/D layout: col = lane&15, row = quad*4 + reg (dtype-independent, m121-128)
    const float sc = (MODE == 2) ? (1.f / 32768.f) : (1.f / 16384.f);
#pragma unroll
    for (int mt = 0; mt < 4; ++mt) {
#pragma unroll
        for (int nt = 0; nt < 4; ++nt) {
            const int n = n0 + wn + nt * 16 + l16;
            const float bvf = bias[n];
#pragma unroll
            for (int i = 0; i < 4; ++i) {
                const int m = m0 + wm + mt * 16 + quad * 4 + i;
                if (m >= M) continue;
                float v = (float)acc[mt][nt][i] * sc + bvf;
                if (MODE == 2) {
                    const size_t idx = (size_t)m * N + n;
                    ((float*)out)[idx] = extra[idx] + v;
                } else {  // MODE 3: quickgelu -> i8 x32
                    float g = v / (1.0f + __expf(-1.702f * v));
                    ((u8*)out)[(size_t)m * N + n] = (u8)q8(g, 32.f);
                }
            }
        }
    }
}

// ---------------- MFMA attention v4 (unchanged) ----------------
#define ATT_PS 296
__global__ __launch_bounds__(256, 4)
void attn_mfma_kernel(const u16* __restrict__ q, const u16* __restrict__ k,
                      const u16* __restrict__ vT, u16* __restrict__ o) {
    __shared__ __align__(16) u16 sP[64 * ATT_PS];
    __shared__ float sInv[64];

    const int t = threadIdx.x;
    const int wave = t >> 6, lane = t & 63;
    const int quad = lane >> 4, l16 = lane & 15;

    const int lid = blockIdx.x;
    const int g = lid / 40, local = lid - g * 40;
    const int qt = local >> 3, x = local & 7;
    const int hb = g * 8 + x;
    const int h = hb & (H_CNT - 1), b = hb >> 4;
    const int q0 = qt * 64;
    const size_t head = (size_t)b * N_SEQ * D_DIM + (size_t)h * HD_DIM;

    int qrow = q0 + wave * 16 + l16; if (qrow > N_SEQ - 1) qrow = N_SEQ - 1;
    const u16* qp = q + head + (size_t)qrow * D_DIM + quad * 8;
    bf16x8 qf0 = *(const bf16x8*)(qp);
    bf16x8 qf1 = *(const bf16x8*)(qp + 32);

    f32x4 s[5][4];
#pragma unroll
    for (int kt = 0; kt < 5; ++kt) {
        const int ntMax = (kt == 4) ? 2 : 4;
#pragma unroll
        for (int nt = 0; nt < 4; ++nt) {
            if (nt >= ntMax) continue;
            s[kt][nt] = {0.f, 0.f, 0.f, 0.f};
            int key = kt * 64 + nt * 16 + l16;
            if (key > N_SEQ - 1) key = N_SEQ - 1;
            const u16* kr = k + head + (size_t)key * D_DIM + quad * 8;
            bf16x8 b0 = *(const bf16x8*)(kr);
            bf16x8 b1 = *(const bf16x8*)(kr + 32);
            s[kt][nt] = __builtin_amdgcn_mfma_f32_16x16x32_bf16(qf0, b0, s[kt][nt], 0, 0, 0);
            s[kt][nt] = __builtin_amdgcn_mfma_f32_16x16x32_bf16(qf1, b1, s[kt][nt], 0, 0, 0);
        }
    }

#pragma unroll
    for (int i = 0; i < 4; ++i) {
        float mx = -1e30f;
#pragma unroll
        for (int kt = 0; kt < 5; ++kt) {
            const int ntMax = (kt == 4) ? 2 : 4;
#pragma unroll
            for (int nt = 0; nt < 4; ++nt) {
                if (nt >= ntMax) continue;
                const bool valid = (kt < 4) || (nt == 0 && l16 == 0);
                if (valid) mx = fmaxf(mx, s[kt][nt][i]);
            }
        }
        mx = fmaxf(mx, __shfl_xor(mx, 1, 64));
        mx = fmaxf(mx, __shfl_xor(mx, 2, 64));
        mx = fmaxf(mx, __shfl_xor(mx, 4, 64));
        mx = fmaxf(mx, __shfl_xor(mx, 8, 64));
        float sum = 0.f;
        const int prow = wave * 16 + quad * 4 + i;
#pragma unroll
        for (int kt = 0; kt < 5; ++kt) {
            const int ntMax = (kt == 4) ? 2 : 4;
#pragma unroll
            for (int nt = 0; nt < 4; ++nt) {
                if (nt >= ntMax) continue;
                const bool valid = (kt < 4) || (nt == 0 && l16 == 0);
                float pv = 0.f;
                if (valid) { pv = __expf(s[kt][nt][i] - mx); sum += pv; }
                sP[prow * ATT_PS + kt * 64 + nt * 16 + l16] = f2b(pv);
            }
        }
        sum += __shfl_xor(sum, 1, 64);
        sum += __shfl_xor(sum, 2, 64);
        sum += __shfl_xor(sum, 4, 64);
        sum += __shfl_xor(sum, 8, 64);
        if (l16 == 0) sInv[prow] = 1.0f / sum;
    }
    __syncthreads();   // required: orders u16 stores vs bf16-vector loads of sP

    f32x4 oacc[4] = {{0.f,0.f,0.f,0.f},{0.f,0.f,0.f,0.f},
                     {0.f,0.f,0.f,0.f},{0.f,0.f,0.f,0.f}};
    const u16* vhead = vT + ((size_t)b * D_DIM + h * HD_DIM) * VT_NP;
    const int prr = wave * 16 + l16;
#pragma unroll
    for (int kt = 0; kt < 5; ++kt) {
        const int j0 = kt * 64;
        bf16x8 p0 = *(const bf16x8*)(sP + prr * ATT_PS + j0 + quad * 8);
        bf16x8 p1;
        if (kt < 4) p1 = *(const bf16x8*)(sP + prr * ATT_PS + j0 + quad * 8 + 32);
#pragma unroll
        for (int nt = 0; nt < 4; ++nt) {
            const u16* vr = vhead + (size_t)(nt * 16 + l16) * VT_NP + j0 + quad * 8;
            bf16x8 b0 = *(const bf16x8*)(vr);
            oacc[nt] = __builtin_amdgcn_mfma_f32_16x16x32_bf16(p0, b0, oacc[nt], 0, 0, 0);
            if (kt < 4) {
                bf16x8 b1 = *(const bf16x8*)(vr + 32);
                oacc[nt] = __builtin_amdgcn_mfma_f32_16x16x32_bf16(p1, b1, oacc[nt], 0, 0, 0);
            }
        }
    }
#pragma unroll
    for (int nt = 0; nt < 4; ++nt) {
#pragma unroll
        for (int i = 0; i < 4; ++i) {
            const int mrow = wave * 16 + quad * 4 + i;
            const int m = q0 + mrow;
            if (m < N_SEQ) {
                o[head + (size_t)m * D_DIM + nt * 16 + l16] =
                    f2b(oacc[nt][i] * sInv[mrow]);
            }
        }
    }
}

extern "C" void kernel_launch(void* const* d_in, const int* in_sizes, int n_in,
                              void* d_out, int out_size, void* d_ws, size_t ws_size,
                              hipStream_t stream) {
    const float* hs   = (const float*)d_in[0];
    const float* ln1w = (const float*)d_in[1];
    const float* ln1b = (const float*)d_in[2];
    const float* wq   = (const float*)d_in[3];
    const float* bq   = (const float*)d_in[4];
    const float* wk   = (const float*)d_in[5];
    const float* bk   = (const float*)d_in[6];
    const float* wv   = (const float*)d_in[7];
    const float* bv   = (const float*)d_in[8];
    const float* wo   = (const float*)d_in[9];
    const float* bo   = (const float*)d_in[10];
    const float* ln2w = (const float*)d_in[11];
    const float* ln2b = (const float*)d_in[12];
    const float* w1   = (const float*)d_in[13];
    const float* b1   = (const float*)d_in[14];
    const float* w2   = (const float*)d_in[15];
    const float* b2   = (const float*)d_in[16];

    char* p = (char*)d_ws;
    size_t off = 0;
    auto alloc = [&](size_t bytes) {
        char* r = p + off;
        off += (bytes + 255) & ~(size_t)255;
        return (void*)r;
    };
    const int M = M_TOK;
    // bf16 weight block: contiguous (cvt_all writes linearly): wqkv | wo
    u16* wqkvb = (u16*)alloc((size_t)3 * D_DIM * D_DIM * 2);
    u16* wob   = (u16*)alloc((size_t)D_DIM * D_DIM * 2);
    u8*  w1i8  = (u8*) alloc((size_t)FF_DIM * D_DIM);
    u8*  w2i8  = (u8*) alloc((size_t)D_DIM * FF_DIM);
    float* bqkv = (float*)alloc((size_t)3 * D_DIM * 4);
    u16*  x_ln = (u16*) alloc((size_t)M * D_DIM * 2);
    u16*  qb   = (u16*) alloc((size_t)M * D_DIM * 2);
    u16*  kb   = (u16*) alloc((size_t)M * D_DIM * 2);
    u16*  vTb  = (u16*) alloc((size_t)B_SZ * D_DIM * VT_NP * 2);
    u16*  ab   = (u16*) alloc((size_t)M * D_DIM * 2);
    float* hid = (float*)alloc((size_t)M * D_DIM * 4);
    // i8 aliases (regions dead after o-proj): h1i8 over qb+kb (42 MB), x2i8 over ab
    u8* h1i8 = (u8*)qb;
    u8* x2i8 = (u8*)ab;

    const int nDD = D_DIM * D_DIM, nFD = FF_DIM * D_DIM;
    const int WB8 = (4 * nDD) / 8, WF8 = (2 * nFD) / 8;
    cvt_all_kernel<<<(WB8 + WF8 + 3 * D_DIM + 255) / 256, 256, 0, stream>>>(
        wq, wk, wv, wo, w1, w2, bq, bk, bv, wqkvb, w1i8, w2i8, bqkv);

    ln_kernel<false><<<M, 256, 0, stream>>>(hs, ln1w, ln1b, x_ln);

    const int gM = (M + 127) / 128;  // 81
    dim3 gQKV(gM, 3 * D_DIM / 128);  // 81 x 24
    gemm_kernel<5><<<gQKV, 256, 0, stream>>>(x_ln, wqkvb, bqkv, nullptr,
                                             qb, kb, vTb, M, 3 * D_DIM, D_DIM, 16);

    attn_mfma_kernel<<<5 * H_CNT * B_SZ, 256, 0, stream>>>(qb, kb, vTb, ab);

    dim3 gD(gM, D_DIM / 128);        // 81 x 8
    gemm_kernel<2><<<gD, 256, 0, stream>>>(ab, wob, bo, hs, hid, nullptr, nullptr,
                                           M, D_DIM, D_DIM, 16);

    ln_kernel<true><<<M, 256, 0, stream>>>(hid, ln2w, ln2b, x2i8);

    dim3 gF(gM, FF_DIM / 128);       // 81 x 32
    gemm_i8_kernel<3><<<gF, 256, 0, stream>>>(x2i8, w1i8, b1, nullptr, h1i8,
                                              M, FF_DIM, D_DIM, 16);
    gemm_i8_kernel<2><<<gD, 256, 0, stream>>>(h1i8, w2i8, b2, hid, (float*)d_out,
                                              M, D_DIM, FF_DIM, 4);
}